// Round 1
// baseline (1222.482 us; speedup 1.0000x reference)
//
#include <hip/hip_runtime.h>
#include <hip/hip_bf16.h>

#define N_NODES   100000
#define N_EDGES   1600000
#define N_GRAPHS  64
#define FDIM      128
#define N_LABELS  20
#define SCAN_BLOCKS 391   // ceil(N_NODES/256)

// ---------------- utility ----------------
__global__ void zero_i32(int* __restrict__ p, int n) {
  int i = blockIdx.x * 256 + threadIdx.x;
  if (i < n) p[i] = 0;
}

// ---------------- embedding gather: h[i,:] = emb[x[i],:] ----------------
__global__ __launch_bounds__(256) void embed_kernel(
    const int* __restrict__ x, const float* __restrict__ emb,
    float* __restrict__ h) {
  int gid  = blockIdx.x * 256 + threadIdx.x;   // N_NODES*32 threads
  int node = gid >> 5;
  int fq   = gid & 31;
  int idx  = x[node];
  ((float4*)(h + (size_t)node * FDIM))[fq] =
      ((const float4*)(emb + (size_t)idx * FDIM))[fq];
}

// ---------------- CSR build ----------------
__global__ void count_kernel(const int* __restrict__ ei, int* __restrict__ deg) {
  int e = blockIdx.x * 256 + threadIdx.x;
  if (e < N_EDGES) atomicAdd(&deg[ei[N_EDGES + e]], 1);
}

// per-block exclusive scan of deg -> offsets ; blockSums[b] = block total
__global__ __launch_bounds__(256) void scan1_kernel(
    const int* __restrict__ deg, int* __restrict__ offsets,
    int* __restrict__ blockSums) {
  __shared__ int s[256];
  int tid = threadIdx.x;
  int i = blockIdx.x * 256 + tid;
  int v = (i < N_NODES) ? deg[i] : 0;
  s[tid] = v;
  __syncthreads();
  for (int off = 1; off < 256; off <<= 1) {
    int t = (tid >= off) ? s[tid - off] : 0;
    __syncthreads();
    s[tid] += t;
    __syncthreads();
  }
  if (i < N_NODES) offsets[i] = s[tid] - v;       // exclusive within block
  if (tid == 255) blockSums[blockIdx.x] = s[255];
}

// exclusive scan of blockSums in place (SCAN_BLOCKS <= 512)
__global__ __launch_bounds__(512) void scan2_kernel(int* __restrict__ blockSums) {
  __shared__ int s[512];
  int tid = threadIdx.x;
  int v = (tid < SCAN_BLOCKS) ? blockSums[tid] : 0;
  s[tid] = v;
  __syncthreads();
  for (int off = 1; off < 512; off <<= 1) {
    int t = (tid >= off) ? s[tid - off] : 0;
    __syncthreads();
    s[tid] += t;
    __syncthreads();
  }
  if (tid < SCAN_BLOCKS) blockSums[tid] = s[tid] - v;
}

// add block offsets; init cursor; set offsets[N]
__global__ __launch_bounds__(256) void scan3_kernel(
    int* __restrict__ offsets, const int* __restrict__ blockSums,
    int* __restrict__ cursor) {
  int i = blockIdx.x * 256 + threadIdx.x;
  if (i < N_NODES) {
    int o = offsets[i] + blockSums[blockIdx.x];
    offsets[i] = o;
    cursor[i] = o;
  }
  if (blockIdx.x == 0 && threadIdx.x == 0) offsets[N_NODES] = N_EDGES;
}

__global__ void fill_kernel(const int* __restrict__ ei,
                            int* __restrict__ cursor,
                            int* __restrict__ csr_src) {
  int e = blockIdx.x * 256 + threadIdx.x;
  if (e < N_EDGES) {
    int s = ei[e];
    int d = ei[N_EDGES + e];
    int p = atomicAdd(&cursor[d], 1);
    csr_src[p] = s;
  }
}

// ---------------- fused GraphConv layer ----------------
// out[i,:] = relu( agg[i,:] @ w_rel + h[i,:] @ w_root + b )
// block = 256 threads = 8 nodes x 32 feature-quads
__global__ __launch_bounds__(256) void layer_kernel(
    const float* __restrict__ hin, const int* __restrict__ offs,
    const int* __restrict__ csr, const float* __restrict__ wrel,
    const float* __restrict__ wroot, const float* __restrict__ bias,
    float* __restrict__ hout) {
  __shared__ float h_s[8][FDIM];
  __shared__ float a_s[8][FDIM];
  int sub = threadIdx.x >> 5;     // node within block (0..7)
  int fq  = threadIdx.x & 31;     // feature quad (0..31)
  int node = blockIdx.x * 8 + sub;

  float4 hv = ((const float4*)(hin + (size_t)node * FDIM))[fq];
  ((float4*)h_s[sub])[fq] = hv;

  float4 acc = make_float4(0.f, 0.f, 0.f, 0.f);
  int s = offs[node], e = offs[node + 1];
  for (int p = s; p < e; ++p) {
    int src = csr[p];   // broadcast within the 32-lane subgroup
    float4 v = ((const float4*)(hin + (size_t)src * FDIM))[fq];
    acc.x += v.x; acc.y += v.y; acc.z += v.z; acc.w += v.w;
  }
  ((float4*)a_s[sub])[fq] = acc;
  __syncthreads();

  float4 o = ((const float4*)bias)[fq];
#pragma unroll 4
  for (int k = 0; k < FDIM; ++k) {
    float a  = a_s[sub][k];
    float hh = h_s[sub][k];
    float4 wr = ((const float4*)(wrel  + k * FDIM))[fq];
    float4 wt = ((const float4*)(wroot + k * FDIM))[fq];
    o.x += a * wr.x + hh * wt.x;
    o.y += a * wr.y + hh * wt.y;
    o.z += a * wr.z + hh * wt.z;
    o.w += a * wr.w + hh * wt.w;
  }
  o.x = fmaxf(o.x, 0.f); o.y = fmaxf(o.y, 0.f);
  o.z = fmaxf(o.z, 0.f); o.w = fmaxf(o.w, 0.f);
  ((float4*)(hout + (size_t)node * FDIM))[fq] = o;
}

// ---------------- per-graph segment boundaries (batch is sorted) ----------------
__global__ void find_starts_kernel(const int* __restrict__ batch,
                                   int* __restrict__ start) {
  int i = blockIdx.x * 256 + threadIdx.x;
  if (i >= N_NODES) return;
  int b  = batch[i];
  int bp = (i == 0) ? -1 : batch[i - 1];
  for (int g = bp + 1; g <= b; ++g) start[g] = i;
  if (i == N_NODES - 1) {
    for (int g = b + 1; g <= N_GRAPHS; ++g) start[g] = N_NODES;
  }
}

// ---------------- pooling: max & sum per graph ----------------
// grid = 64 graphs * 8 chunks, block = 128 (one feature each)
// pool[g*256 + f]       = max (via uint atomicMax, valid since values >= 0)
// pool[g*256 + 128 + f] = sum (atomicAdd), divided by count in pool_fin
__global__ __launch_bounds__(128) void pool_kernel(
    const float* __restrict__ h2, const int* __restrict__ start,
    float* __restrict__ pool) {
  int g = blockIdx.x >> 3;
  int c = blockIdx.x & 7;
  int f = threadIdx.x;
  int s = start[g], e = start[g + 1];
  int len = e - s;
  int lo = s + (int)(((long long)len * c) >> 3);
  int hi = s + (int)(((long long)len * (c + 1)) >> 3);
  float mx = 0.f, sm = 0.f;
  for (int n = lo; n < hi; ++n) {
    float v = h2[(size_t)n * FDIM + f];
    mx = fmaxf(mx, v);
    sm += v;
  }
  atomicMax((unsigned int*)&pool[g * 256 + f], __float_as_uint(mx));
  atomicAdd(&pool[g * 256 + 128 + f], sm);
}

__global__ void pool_fin_kernel(float* __restrict__ pool,
                                const int* __restrict__ start) {
  int gid = blockIdx.x * 256 + threadIdx.x;   // 8192
  int g = gid >> 7, f = gid & 127;
  int cnt = start[g + 1] - start[g];
  float c = (float)(cnt > 1 ? cnt : 1);
  pool[g * 256 + 128 + f] /= c;
}

// ---------------- MLP head ----------------
__global__ void head1_kernel(const float* __restrict__ pool,
                             const float* __restrict__ lw1,
                             const float* __restrict__ lb1,
                             float* __restrict__ t1) {
  int gid = blockIdx.x * 256 + threadIdx.x;   // 8192
  int r = gid >> 7, c = gid & 127;
  float acc = lb1[c];
  for (int k = 0; k < 256; ++k) acc += pool[r * 256 + k] * lw1[k * 128 + c];
  t1[gid] = fmaxf(acc, 0.f);
}

__global__ void head2_kernel(const float* __restrict__ t1,
                             const float* __restrict__ lw2,
                             const float* __restrict__ lb2,
                             float* __restrict__ t2) {
  int gid = blockIdx.x * 256 + threadIdx.x;   // 4096
  int r = gid >> 6, c = gid & 63;
  float acc = lb2[c];
  for (int k = 0; k < 128; ++k) acc += t1[r * 128 + k] * lw2[k * 64 + c];
  t2[gid] = fmaxf(acc, 0.f);
}

// logits + log_softmax over axis 0 (the graph axis), single block
__global__ __launch_bounds__(256) void head3_kernel(
    const float* __restrict__ t2, const float* __restrict__ lw3,
    const float* __restrict__ lb3, float* __restrict__ out) {
  __shared__ float lg[N_GRAPHS * N_LABELS];
  __shared__ float col[N_LABELS];
  int tid = threadIdx.x;
  for (int o = tid; o < N_GRAPHS * N_LABELS; o += 256) {
    int r = o / N_LABELS, c = o - r * N_LABELS;
    float acc = lb3[c];
    for (int k = 0; k < 64; ++k) acc += t2[r * 64 + k] * lw3[k * N_LABELS + c];
    lg[o] = acc;
  }
  __syncthreads();
  if (tid < N_LABELS) {
    float m = -1e30f;
    for (int r = 0; r < N_GRAPHS; ++r) m = fmaxf(m, lg[r * N_LABELS + tid]);
    float s = 0.f;
    for (int r = 0; r < N_GRAPHS; ++r) s += expf(lg[r * N_LABELS + tid] - m);
    col[tid] = m + logf(s);
  }
  __syncthreads();
  for (int o = tid; o < N_GRAPHS * N_LABELS; o += 256) {
    int c = o % N_LABELS;
    out[o] = lg[o] - col[c];
  }
}

// ---------------- launch ----------------
extern "C" void kernel_launch(void* const* d_in, const int* in_sizes, int n_in,
                              void* d_out, int out_size, void* d_ws, size_t ws_size,
                              hipStream_t stream) {
  const int*   x     = (const int*)  d_in[0];
  const int*   ei    = (const int*)  d_in[1];
  const int*   batch = (const int*)  d_in[2];
  const float* emb   = (const float*)d_in[3];
  const float* w1rel = (const float*)d_in[4];
  const float* w1rt  = (const float*)d_in[5];
  const float* b1    = (const float*)d_in[6];
  const float* w2rel = (const float*)d_in[7];
  const float* w2rt  = (const float*)d_in[8];
  const float* b2    = (const float*)d_in[9];
  const float* lw1   = (const float*)d_in[10];
  const float* lb1   = (const float*)d_in[11];
  const float* lw2   = (const float*)d_in[12];
  const float* lb2   = (const float*)d_in[13];
  const float* lw3   = (const float*)d_in[14];
  const float* lb3   = (const float*)d_in[15];
  float* out = (float*)d_out;

  char* ws = (char*)d_ws;
  const size_t HBYTES = (size_t)N_NODES * FDIM * 4;   // 51,200,000
  float* hA      = (float*)(ws);
  float* hB      = (float*)(ws + HBYTES);
  int*   deg     = (int*)  (ws + 2 * HBYTES);
  int*   offsets = (int*)  (ws + 2 * HBYTES + 400128);
  int*   cursor  = (int*)  (ws + 2 * HBYTES + 2 * 400128);
  int*   bsum    = (int*)  (ws + 2 * HBYTES + 3 * 400128);
  int*   csr     = (int*)  (ws + 2 * HBYTES + 3 * 400128 + 2048);
  int*   start   = (int*)  (ws + 2 * HBYTES + 3 * 400128 + 2048 + 6400000);
  float* pool    = (float*)(ws + 2 * HBYTES + 3 * 400128 + 2048 + 6400000 + 512);
  float* t1      = (float*)(ws + 2 * HBYTES + 3 * 400128 + 2048 + 6400000 + 512 + 65536);
  float* t2      = (float*)(ws + 2 * HBYTES + 3 * 400128 + 2048 + 6400000 + 512 + 65536 + 32768);

  // zero deg + pool (ws is poisoned 0xAA before every launch)
  zero_i32<<<SCAN_BLOCKS, 256, 0, stream>>>(deg, N_NODES);
  zero_i32<<<64, 256, 0, stream>>>((int*)pool, N_GRAPHS * 256);

  embed_kernel<<<N_NODES * 32 / 256, 256, 0, stream>>>(x, emb, hA);

  count_kernel<<<(N_EDGES + 255) / 256, 256, 0, stream>>>(ei, deg);
  scan1_kernel<<<SCAN_BLOCKS, 256, 0, stream>>>(deg, offsets, bsum);
  scan2_kernel<<<1, 512, 0, stream>>>(bsum);
  scan3_kernel<<<SCAN_BLOCKS, 256, 0, stream>>>(offsets, bsum, cursor);
  fill_kernel<<<(N_EDGES + 255) / 256, 256, 0, stream>>>(ei, cursor, csr);

  layer_kernel<<<N_NODES / 8, 256, 0, stream>>>(hA, offsets, csr, w1rel, w1rt, b1, hB);
  layer_kernel<<<N_NODES / 8, 256, 0, stream>>>(hB, offsets, csr, w2rel, w2rt, b2, hA);

  find_starts_kernel<<<SCAN_BLOCKS, 256, 0, stream>>>(batch, start);
  pool_kernel<<<N_GRAPHS * 8, 128, 0, stream>>>(hA, start, pool);
  pool_fin_kernel<<<32, 256, 0, stream>>>(pool, start);

  head1_kernel<<<32, 256, 0, stream>>>(pool, lw1, lb1, t1);
  head2_kernel<<<16, 256, 0, stream>>>(t1, lw2, lb2, t2);
  head3_kernel<<<1, 256, 0, stream>>>(t2, lw3, lb3, out);
}

// Round 2
// 1203.134 us; speedup vs baseline: 1.0161x; 1.0161x over previous
//
#include <hip/hip_runtime.h>
#include <hip/hip_bf16.h>

#define N_NODES   100000
#define N_EDGES   1600000
#define N_GRAPHS  64
#define FDIM      128
#define N_LABELS  20
#define SCAN_BLOCKS 391   // ceil(N_NODES/256)
#define ZROW      N_NODES // index of the all-zero dummy row

// ---------------- utility ----------------
__global__ void zero_i32(int* __restrict__ p, int n) {
  int i = blockIdx.x * 256 + threadIdx.x;
  if (i < n) p[i] = 0;
}

// zero the dummy rows of hA/hB and pad csr tail with valid indices
__global__ void zero_aux_kernel(float* __restrict__ hA, float* __restrict__ hB,
                                int* __restrict__ csr) {
  int f = threadIdx.x;   // 128
  hA[(size_t)ZROW * FDIM + f] = 0.f;
  hB[(size_t)ZROW * FDIM + f] = 0.f;
  if (f < 8) csr[N_EDGES + f] = 0;  // valid node id; never accumulated
}

// ---------------- embedding gather: h[i,:] = emb[x[i],:] ----------------
__global__ __launch_bounds__(256) void embed_kernel(
    const int* __restrict__ x, const float* __restrict__ emb,
    float* __restrict__ h) {
  int gid  = blockIdx.x * 256 + threadIdx.x;   // N_NODES*32 threads
  int node = gid >> 5;
  int fq   = gid & 31;
  int idx  = x[node];
  ((float4*)(h + (size_t)node * FDIM))[fq] =
      ((const float4*)(emb + (size_t)idx * FDIM))[fq];
}

// ---------------- CSR build ----------------
__global__ void count_kernel(const int* __restrict__ ei, int* __restrict__ deg) {
  int e = blockIdx.x * 256 + threadIdx.x;
  if (e < N_EDGES) atomicAdd(&deg[ei[N_EDGES + e]], 1);
}

__global__ __launch_bounds__(256) void scan1_kernel(
    const int* __restrict__ deg, int* __restrict__ offsets,
    int* __restrict__ blockSums) {
  __shared__ int s[256];
  int tid = threadIdx.x;
  int i = blockIdx.x * 256 + tid;
  int v = (i < N_NODES) ? deg[i] : 0;
  s[tid] = v;
  __syncthreads();
  for (int off = 1; off < 256; off <<= 1) {
    int t = (tid >= off) ? s[tid - off] : 0;
    __syncthreads();
    s[tid] += t;
    __syncthreads();
  }
  if (i < N_NODES) offsets[i] = s[tid] - v;       // exclusive within block
  if (tid == 255) blockSums[blockIdx.x] = s[255];
}

__global__ __launch_bounds__(512) void scan2_kernel(int* __restrict__ blockSums) {
  __shared__ int s[512];
  int tid = threadIdx.x;
  int v = (tid < SCAN_BLOCKS) ? blockSums[tid] : 0;
  s[tid] = v;
  __syncthreads();
  for (int off = 1; off < 512; off <<= 1) {
    int t = (tid >= off) ? s[tid - off] : 0;
    __syncthreads();
    s[tid] += t;
    __syncthreads();
  }
  if (tid < SCAN_BLOCKS) blockSums[tid] = s[tid] - v;
}

__global__ __launch_bounds__(256) void scan3_kernel(
    int* __restrict__ offsets, const int* __restrict__ blockSums,
    int* __restrict__ cursor) {
  int i = blockIdx.x * 256 + threadIdx.x;
  if (i < N_NODES) {
    int o = offsets[i] + blockSums[blockIdx.x];
    offsets[i] = o;
    cursor[i] = o;
  }
  if (blockIdx.x == 0 && threadIdx.x == 0) offsets[N_NODES] = N_EDGES;
}

__global__ void fill_kernel(const int* __restrict__ ei,
                            int* __restrict__ cursor,
                            int* __restrict__ csr_src) {
  int e = blockIdx.x * 256 + threadIdx.x;
  if (e < N_EDGES) {
    int s = ei[e];
    int d = ei[N_EDGES + e];
    int p = atomicAdd(&cursor[d], 1);
    csr_src[p] = s;
  }
}

// ---------------- fused GraphConv layer ----------------
// out[i,:] = relu( agg[i,:] @ w_rel + h[i,:] @ w_root + b )
// block = 256 threads = 8 nodes x 32 feature-quads
// Edge gather is 8-deep unrolled: 8 row-gathers in flight per subgroup.
// Tail entries are redirected to the zero row (ZROW) so the loop shape is
// uniform and fully pipelined; csr is padded with 8 valid entries.
__global__ __launch_bounds__(256) void layer_kernel(
    const float* __restrict__ hin, const int* __restrict__ offs,
    const int* __restrict__ csr, const float* __restrict__ wrel,
    const float* __restrict__ wroot, const float* __restrict__ bias,
    float* __restrict__ hout) {
  __shared__ float h_s[8][FDIM];
  __shared__ float a_s[8][FDIM];
  int sub = threadIdx.x >> 5;     // node within block (0..7)
  int fq  = threadIdx.x & 31;     // feature quad (0..31)
  int node = blockIdx.x * 8 + sub;
  const float4* __restrict__ hin4 = (const float4*)hin;

  float4 hv = hin4[(size_t)node * 32 + fq];
  ((float4*)h_s[sub])[fq] = hv;

  float4 acc0 = make_float4(0.f, 0.f, 0.f, 0.f);
  float4 acc1 = make_float4(0.f, 0.f, 0.f, 0.f);
  int s = offs[node], e = offs[node + 1];
  for (int p = s; p < e; p += 8) {
    int idx[8];
#pragma unroll
    for (int u = 0; u < 8; ++u) {
      int iu = csr[p + u];                 // safe: csr padded by 8
      idx[u] = (p + u < e) ? iu : ZROW;    // tail -> zero row
    }
    float4 v0 = hin4[(size_t)idx[0] * 32 + fq];
    float4 v1 = hin4[(size_t)idx[1] * 32 + fq];
    float4 v2 = hin4[(size_t)idx[2] * 32 + fq];
    float4 v3 = hin4[(size_t)idx[3] * 32 + fq];
    float4 v4 = hin4[(size_t)idx[4] * 32 + fq];
    float4 v5 = hin4[(size_t)idx[5] * 32 + fq];
    float4 v6 = hin4[(size_t)idx[6] * 32 + fq];
    float4 v7 = hin4[(size_t)idx[7] * 32 + fq];
    acc0.x += v0.x + v2.x + v4.x + v6.x;
    acc0.y += v0.y + v2.y + v4.y + v6.y;
    acc0.z += v0.z + v2.z + v4.z + v6.z;
    acc0.w += v0.w + v2.w + v4.w + v6.w;
    acc1.x += v1.x + v3.x + v5.x + v7.x;
    acc1.y += v1.y + v3.y + v5.y + v7.y;
    acc1.z += v1.z + v3.z + v5.z + v7.z;
    acc1.w += v1.w + v3.w + v5.w + v7.w;
  }
  float4 acc = make_float4(acc0.x + acc1.x, acc0.y + acc1.y,
                           acc0.z + acc1.z, acc0.w + acc1.w);
  ((float4*)a_s[sub])[fq] = acc;
  __syncthreads();

  float4 o = ((const float4*)bias)[fq];
#pragma unroll 4
  for (int k = 0; k < FDIM; ++k) {
    float a  = a_s[sub][k];
    float hh = h_s[sub][k];
    float4 wr = ((const float4*)(wrel  + k * FDIM))[fq];
    float4 wt = ((const float4*)(wroot + k * FDIM))[fq];
    o.x += a * wr.x + hh * wt.x;
    o.y += a * wr.y + hh * wt.y;
    o.z += a * wr.z + hh * wt.z;
    o.w += a * wr.w + hh * wt.w;
  }
  o.x = fmaxf(o.x, 0.f); o.y = fmaxf(o.y, 0.f);
  o.z = fmaxf(o.z, 0.f); o.w = fmaxf(o.w, 0.f);
  ((float4*)(hout + (size_t)node * FDIM))[fq] = o;
}

// ---------------- per-graph segment boundaries (batch is sorted) ----------------
__global__ void find_starts_kernel(const int* __restrict__ batch,
                                   int* __restrict__ start) {
  int i = blockIdx.x * 256 + threadIdx.x;
  if (i >= N_NODES) return;
  int b  = batch[i];
  int bp = (i == 0) ? -1 : batch[i - 1];
  for (int g = bp + 1; g <= b; ++g) start[g] = i;
  if (i == N_NODES - 1) {
    for (int g = b + 1; g <= N_GRAPHS; ++g) start[g] = N_NODES;
  }
}

// ---------------- pooling: max & sum per graph ----------------
__global__ __launch_bounds__(128) void pool_kernel(
    const float* __restrict__ h2, const int* __restrict__ start,
    float* __restrict__ pool) {
  int g = blockIdx.x >> 3;
  int c = blockIdx.x & 7;
  int f = threadIdx.x;
  int s = start[g], e = start[g + 1];
  int len = e - s;
  int lo = s + (int)(((long long)len * c) >> 3);
  int hi = s + (int)(((long long)len * (c + 1)) >> 3);
  float mx = 0.f, sm = 0.f;
  for (int n = lo; n < hi; ++n) {
    float v = h2[(size_t)n * FDIM + f];
    mx = fmaxf(mx, v);
    sm += v;
  }
  atomicMax((unsigned int*)&pool[g * 256 + f], __float_as_uint(mx));
  atomicAdd(&pool[g * 256 + 128 + f], sm);
}

__global__ void pool_fin_kernel(float* __restrict__ pool,
                                const int* __restrict__ start) {
  int gid = blockIdx.x * 256 + threadIdx.x;   // 8192
  int g = gid >> 7, f = gid & 127;
  int cnt = start[g + 1] - start[g];
  float c = (float)(cnt > 1 ? cnt : 1);
  pool[g * 256 + 128 + f] /= c;
}

// ---------------- MLP head ----------------
__global__ void head1_kernel(const float* __restrict__ pool,
                             const float* __restrict__ lw1,
                             const float* __restrict__ lb1,
                             float* __restrict__ t1) {
  int gid = blockIdx.x * 256 + threadIdx.x;   // 8192
  int r = gid >> 7, c = gid & 127;
  float acc = lb1[c];
  for (int k = 0; k < 256; ++k) acc += pool[r * 256 + k] * lw1[k * 128 + c];
  t1[gid] = fmaxf(acc, 0.f);
}

__global__ void head2_kernel(const float* __restrict__ t1,
                             const float* __restrict__ lw2,
                             const float* __restrict__ lb2,
                             float* __restrict__ t2) {
  int gid = blockIdx.x * 256 + threadIdx.x;   // 4096
  int r = gid >> 6, c = gid & 63;
  float acc = lb2[c];
  for (int k = 0; k < 128; ++k) acc += t1[r * 128 + k] * lw2[k * 64 + c];
  t2[gid] = fmaxf(acc, 0.f);
}

__global__ __launch_bounds__(256) void head3_kernel(
    const float* __restrict__ t2, const float* __restrict__ lw3,
    const float* __restrict__ lb3, float* __restrict__ out) {
  __shared__ float lg[N_GRAPHS * N_LABELS];
  __shared__ float col[N_LABELS];
  int tid = threadIdx.x;
  for (int o = tid; o < N_GRAPHS * N_LABELS; o += 256) {
    int r = o / N_LABELS, c = o - r * N_LABELS;
    float acc = lb3[c];
    for (int k = 0; k < 64; ++k) acc += t2[r * 64 + k] * lw3[k * N_LABELS + c];
    lg[o] = acc;
  }
  __syncthreads();
  if (tid < N_LABELS) {
    float m = -1e30f;
    for (int r = 0; r < N_GRAPHS; ++r) m = fmaxf(m, lg[r * N_LABELS + tid]);
    float s = 0.f;
    for (int r = 0; r < N_GRAPHS; ++r) s += expf(lg[r * N_LABELS + tid] - m);
    col[tid] = m + logf(s);
  }
  __syncthreads();
  for (int o = tid; o < N_GRAPHS * N_LABELS; o += 256) {
    int c = o % N_LABELS;
    out[o] = lg[o] - col[c];
  }
}

// ---------------- launch ----------------
extern "C" void kernel_launch(void* const* d_in, const int* in_sizes, int n_in,
                              void* d_out, int out_size, void* d_ws, size_t ws_size,
                              hipStream_t stream) {
  const int*   x     = (const int*)  d_in[0];
  const int*   ei    = (const int*)  d_in[1];
  const int*   batch = (const int*)  d_in[2];
  const float* emb   = (const float*)d_in[3];
  const float* w1rel = (const float*)d_in[4];
  const float* w1rt  = (const float*)d_in[5];
  const float* b1    = (const float*)d_in[6];
  const float* w2rel = (const float*)d_in[7];
  const float* w2rt  = (const float*)d_in[8];
  const float* b2    = (const float*)d_in[9];
  const float* lw1   = (const float*)d_in[10];
  const float* lb1   = (const float*)d_in[11];
  const float* lw2   = (const float*)d_in[12];
  const float* lb2   = (const float*)d_in[13];
  const float* lw3   = (const float*)d_in[14];
  const float* lb3   = (const float*)d_in[15];
  float* out = (float*)d_out;

  char* ws = (char*)d_ws;
  const size_t HB = 51201024;          // (N_NODES+1)*FDIM*4 rounded up
  const size_t OFFB = 400128;          // (N_NODES+1) ints rounded up
  const size_t CSRB = 6400512;         // (N_EDGES+8) ints rounded up
  float* hA      = (float*)(ws);
  float* hB      = (float*)(ws + HB);
  int*   deg     = (int*)  (ws + 2 * HB);
  int*   offsets = (int*)  (ws + 2 * HB + OFFB);
  int*   cursor  = (int*)  (ws + 2 * HB + 2 * OFFB);
  int*   bsum    = (int*)  (ws + 2 * HB + 3 * OFFB);
  int*   csr     = (int*)  (ws + 2 * HB + 3 * OFFB + 2048);
  int*   start   = (int*)  (ws + 2 * HB + 3 * OFFB + 2048 + CSRB);
  float* pool    = (float*)(ws + 2 * HB + 3 * OFFB + 2048 + CSRB + 512);
  float* t1      = (float*)(ws + 2 * HB + 3 * OFFB + 2048 + CSRB + 512 + 65536);
  float* t2      = (float*)(ws + 2 * HB + 3 * OFFB + 2048 + CSRB + 512 + 65536 + 32768);

  zero_i32<<<SCAN_BLOCKS, 256, 0, stream>>>(deg, N_NODES);
  zero_i32<<<64, 256, 0, stream>>>((int*)pool, N_GRAPHS * 256);
  zero_aux_kernel<<<1, 128, 0, stream>>>(hA, hB, csr);

  embed_kernel<<<N_NODES * 32 / 256, 256, 0, stream>>>(x, emb, hA);

  count_kernel<<<(N_EDGES + 255) / 256, 256, 0, stream>>>(ei, deg);
  scan1_kernel<<<SCAN_BLOCKS, 256, 0, stream>>>(deg, offsets, bsum);
  scan2_kernel<<<1, 512, 0, stream>>>(bsum);
  scan3_kernel<<<SCAN_BLOCKS, 256, 0, stream>>>(offsets, bsum, cursor);
  fill_kernel<<<(N_EDGES + 255) / 256, 256, 0, stream>>>(ei, cursor, csr);

  layer_kernel<<<N_NODES / 8, 256, 0, stream>>>(hA, offsets, csr, w1rel, w1rt, b1, hB);
  layer_kernel<<<N_NODES / 8, 256, 0, stream>>>(hB, offsets, csr, w2rel, w2rt, b2, hA);

  find_starts_kernel<<<SCAN_BLOCKS, 256, 0, stream>>>(batch, start);
  pool_kernel<<<N_GRAPHS * 8, 128, 0, stream>>>(hA, start, pool);
  pool_fin_kernel<<<32, 256, 0, stream>>>(pool, start);

  head1_kernel<<<32, 256, 0, stream>>>(pool, lw1, lb1, t1);
  head2_kernel<<<16, 256, 0, stream>>>(t1, lw2, lb2, t2);
  head3_kernel<<<1, 256, 0, stream>>>(t2, lw3, lb3, out);
}

// Round 3
// 993.440 us; speedup vs baseline: 1.2306x; 1.2111x over previous
//
#include <hip/hip_runtime.h>
#include <hip/hip_bf16.h>

#define N_NODES   100000
#define N_EDGES   1600000
#define N_GRAPHS  64
#define FDIM      128
#define N_LABELS  20
#define SCAN_BLOCKS 391   // ceil(N_NODES/256)
#define TN        32      // nodes per gemm block
#define APAD      260     // 256 + 4 pad (keeps 16B alignment, breaks bank stride)

// ---------------- init: zero deg, pool, zrow, csr pads ----------------
__global__ __launch_bounds__(256) void init_kernel(
    int* __restrict__ deg, float* __restrict__ pool, float* __restrict__ zrow,
    int* __restrict__ csr, int* __restrict__ csr2) {
  int i = blockIdx.x * 256 + threadIdx.x;
  if (i < N_NODES) deg[i] = 0;
  if (i < N_GRAPHS * 256) pool[i] = 0.f;
  if (i < FDIM) zrow[i] = 0.f;
  if (i < 8) { csr[N_EDGES + i] = 0; csr2[N_EDGES + i] = 0; }
}

// ---------------- CSR build ----------------
__global__ void count_kernel(const int* __restrict__ ei, int* __restrict__ deg) {
  int e = blockIdx.x * 256 + threadIdx.x;
  if (e < N_EDGES) atomicAdd(&deg[ei[N_EDGES + e]], 1);
}

__global__ __launch_bounds__(256) void scan1_kernel(
    const int* __restrict__ deg, int* __restrict__ offsets,
    int* __restrict__ blockSums) {
  __shared__ int s[256];
  int tid = threadIdx.x;
  int i = blockIdx.x * 256 + tid;
  int v = (i < N_NODES) ? deg[i] : 0;
  s[tid] = v;
  __syncthreads();
  for (int off = 1; off < 256; off <<= 1) {
    int t = (tid >= off) ? s[tid - off] : 0;
    __syncthreads();
    s[tid] += t;
    __syncthreads();
  }
  if (i < N_NODES) offsets[i] = s[tid] - v;       // exclusive within block
  if (tid == 255) blockSums[blockIdx.x] = s[255];
}

__global__ __launch_bounds__(512) void scan2_kernel(int* __restrict__ blockSums) {
  __shared__ int s[512];
  int tid = threadIdx.x;
  int v = (tid < SCAN_BLOCKS) ? blockSums[tid] : 0;
  s[tid] = v;
  __syncthreads();
  for (int off = 1; off < 512; off <<= 1) {
    int t = (tid >= off) ? s[tid - off] : 0;
    __syncthreads();
    s[tid] += t;
    __syncthreads();
  }
  if (tid < SCAN_BLOCKS) blockSums[tid] = s[tid] - v;
}

__global__ __launch_bounds__(256) void scan3_kernel(
    int* __restrict__ offsets, const int* __restrict__ blockSums,
    int* __restrict__ cursor) {
  int i = blockIdx.x * 256 + threadIdx.x;
  if (i < N_NODES) {
    int o = offsets[i] + blockSums[blockIdx.x];
    offsets[i] = o;
    cursor[i] = o;
  }
  if (blockIdx.x == 0 && threadIdx.x == 0) offsets[N_NODES] = N_EDGES;
}

// csr[p] = src node id; csr2[p] = x[src] (emb row for layer-1 gather)
__global__ void fill_kernel(const int* __restrict__ ei, const int* __restrict__ x,
                            int* __restrict__ cursor,
                            int* __restrict__ csr, int* __restrict__ csr2) {
  int e = blockIdx.x * 256 + threadIdx.x;
  if (e < N_EDGES) {
    int s = ei[e];
    int d = ei[N_EDGES + e];
    int p = atomicAdd(&cursor[d], 1);
    csr[p] = s;
    csr2[p] = x[s];
  }
}

// ---------------- aggregation: agg[i,:] = sum_{j->i} feat[srcidx[j],:] ----------------
// 256 threads = 8 subs x 32 lanes; 1 node per sub; 8-deep unrolled gather.
// Tail loads are redirected to the zero row (pointer select, never OOB).
__global__ __launch_bounds__(256) void agg_kernel(
    const float* __restrict__ feat, const int* __restrict__ srcidx,
    const int* __restrict__ offs, const float* __restrict__ zrow,
    float* __restrict__ aggout) {
  int sub = threadIdx.x >> 5;
  int fq  = threadIdx.x & 31;
  int node = blockIdx.x * 8 + sub;
  const float4* __restrict__ f4 = (const float4*)feat;
  const float4* __restrict__ z4 = (const float4*)zrow;

  float4 acc0 = make_float4(0.f, 0.f, 0.f, 0.f);
  float4 acc1 = make_float4(0.f, 0.f, 0.f, 0.f);
  int s = offs[node], e = offs[node + 1];
  for (int p = s; p < e; p += 8) {
    const float4* rp[8];
#pragma unroll
    for (int u = 0; u < 8; ++u) {
      int iu = srcidx[p + u];                       // safe: padded by 8
      rp[u] = (p + u < e) ? (f4 + (size_t)iu * 32) : z4;
    }
    float4 v0 = rp[0][fq];
    float4 v1 = rp[1][fq];
    float4 v2 = rp[2][fq];
    float4 v3 = rp[3][fq];
    float4 v4 = rp[4][fq];
    float4 v5 = rp[5][fq];
    float4 v6 = rp[6][fq];
    float4 v7 = rp[7][fq];
    acc0.x += v0.x + v2.x + v4.x + v6.x;
    acc0.y += v0.y + v2.y + v4.y + v6.y;
    acc0.z += v0.z + v2.z + v4.z + v6.z;
    acc0.w += v0.w + v2.w + v4.w + v6.w;
    acc1.x += v1.x + v3.x + v5.x + v7.x;
    acc1.y += v1.y + v3.y + v5.y + v7.y;
    acc1.z += v1.z + v3.z + v5.z + v7.z;
    acc1.w += v1.w + v3.w + v5.w + v7.w;
  }
  float4 a = make_float4(acc0.x + acc1.x, acc0.y + acc1.y,
                         acc0.z + acc1.z, acc0.w + acc1.w);
  ((float4*)aggout)[(size_t)node * 32 + fq] = a;
}

// ---------------- GEMM: hout = relu([agg | h] @ [wrel; wroot] + b) ----------------
// 32 nodes/block, 256 threads. Thread (tr,tc): nodes {2tr,2tr+1}, cols 8tc..8tc+7.
// h rows come from hsrc[hidx[n]] (layer 1: emb via x) or hsrc[n] (hidx==null).
// In-place hsrc==hout is safe: each block reads only the rows it writes,
// staged into LDS before the barrier.
__global__ __launch_bounds__(256) void gemm_kernel(
    const float* __restrict__ agg, const float* __restrict__ hsrc,
    const int* __restrict__ hidx,
    const float* __restrict__ wrel, const float* __restrict__ wroot,
    const float* __restrict__ bias, float* __restrict__ hout) {
  __shared__ float A[TN][APAD];
  int tid = threadIdx.x;
  int nodeBase = blockIdx.x * TN;

  // stage A tile: 8 threads per node, coalesced float4 loads
  {
    int n = tid >> 3;          // 0..31
    int q = tid & 7;           // 0..7
    int gnode = nodeBase + n;
    const float4* ag4 = (const float4*)(agg + (size_t)gnode * FDIM);
    int hrow = hidx ? hidx[gnode] : gnode;
    const float4* h4 = (const float4*)(hsrc + (size_t)hrow * FDIM);
    float4* Ar0 = (float4*)&A[n][0];
    float4* Ar1 = (float4*)&A[n][FDIM];
#pragma unroll
    for (int j = q; j < 32; j += 8) Ar0[j] = ag4[j];
#pragma unroll
    for (int j = q; j < 32; j += 8) Ar1[j] = h4[j];
  }
  __syncthreads();

  int tc = tid & 15, tr = tid >> 4;
  int n0 = tr * 2;
  int c0 = tc * 8;

  float acc0[8], acc1[8];
  {
    float4 ba = *(const float4*)&bias[c0];
    float4 bb = *(const float4*)&bias[c0 + 4];
    acc0[0] = ba.x; acc0[1] = ba.y; acc0[2] = ba.z; acc0[3] = ba.w;
    acc0[4] = bb.x; acc0[5] = bb.y; acc0[6] = bb.z; acc0[7] = bb.w;
#pragma unroll
    for (int j = 0; j < 8; ++j) acc1[j] = acc0[j];
  }

#pragma unroll
  for (int half = 0; half < 2; ++half) {
    const float* __restrict__ W = half ? wroot : wrel;
    const float* Ar0 = &A[n0][half * FDIM];
    const float* Ar1 = &A[n0 + 1][half * FDIM];
    for (int k0 = 0; k0 < FDIM; k0 += 4) {
      float4 a0 = *(const float4*)(Ar0 + k0);
      float4 a1 = *(const float4*)(Ar1 + k0);
      float a0v[4] = {a0.x, a0.y, a0.z, a0.w};
      float a1v[4] = {a1.x, a1.y, a1.z, a1.w};
#pragma unroll
      for (int kk = 0; kk < 4; ++kk) {
        const float* w = W + (size_t)(k0 + kk) * FDIM + c0;
        float4 w0 = *(const float4*)w;
        float4 w1 = *(const float4*)(w + 4);
        float wv[8] = {w0.x, w0.y, w0.z, w0.w, w1.x, w1.y, w1.z, w1.w};
#pragma unroll
        for (int j = 0; j < 8; ++j) {
          acc0[j] += a0v[kk] * wv[j];
          acc1[j] += a1v[kk] * wv[j];
        }
      }
    }
  }

  // epilogue: relu + store
  float* out0 = hout + (size_t)(nodeBase + n0) * FDIM + c0;
  float* out1 = out0 + FDIM;
  float4 o;
  o.x = fmaxf(acc0[0], 0.f); o.y = fmaxf(acc0[1], 0.f);
  o.z = fmaxf(acc0[2], 0.f); o.w = fmaxf(acc0[3], 0.f);
  *(float4*)out0 = o;
  o.x = fmaxf(acc0[4], 0.f); o.y = fmaxf(acc0[5], 0.f);
  o.z = fmaxf(acc0[6], 0.f); o.w = fmaxf(acc0[7], 0.f);
  *(float4*)(out0 + 4) = o;
  o.x = fmaxf(acc1[0], 0.f); o.y = fmaxf(acc1[1], 0.f);
  o.z = fmaxf(acc1[2], 0.f); o.w = fmaxf(acc1[3], 0.f);
  *(float4*)out1 = o;
  o.x = fmaxf(acc1[4], 0.f); o.y = fmaxf(acc1[5], 0.f);
  o.z = fmaxf(acc1[6], 0.f); o.w = fmaxf(acc1[7], 0.f);
  *(float4*)(out1 + 4) = o;
}

// ---------------- per-graph segment boundaries (batch is sorted) ----------------
__global__ void find_starts_kernel(const int* __restrict__ batch,
                                   int* __restrict__ start) {
  int i = blockIdx.x * 256 + threadIdx.x;
  if (i >= N_NODES) return;
  int b  = batch[i];
  int bp = (i == 0) ? -1 : batch[i - 1];
  for (int g = bp + 1; g <= b; ++g) start[g] = i;
  if (i == N_NODES - 1) {
    for (int g = b + 1; g <= N_GRAPHS; ++g) start[g] = N_NODES;
  }
}

// ---------------- pooling: max & sum per graph ----------------
__global__ __launch_bounds__(128) void pool_kernel(
    const float* __restrict__ h2, const int* __restrict__ start,
    float* __restrict__ pool) {
  int g = blockIdx.x >> 3;
  int c = blockIdx.x & 7;
  int f = threadIdx.x;
  int s = start[g], e = start[g + 1];
  int len = e - s;
  int lo = s + (int)(((long long)len * c) >> 3);
  int hi = s + (int)(((long long)len * (c + 1)) >> 3);
  float mx = 0.f, sm = 0.f;
  for (int n = lo; n < hi; ++n) {
    float v = h2[(size_t)n * FDIM + f];
    mx = fmaxf(mx, v);
    sm += v;
  }
  atomicMax((unsigned int*)&pool[g * 256 + f], __float_as_uint(mx));
  atomicAdd(&pool[g * 256 + 128 + f], sm);
}

__global__ void pool_fin_kernel(float* __restrict__ pool,
                                const int* __restrict__ start) {
  int gid = blockIdx.x * 256 + threadIdx.x;   // 8192
  int g = gid >> 7, f = gid & 127;
  int cnt = start[g + 1] - start[g];
  float c = (float)(cnt > 1 ? cnt : 1);
  pool[g * 256 + 128 + f] /= c;
}

// ---------------- MLP head ----------------
__global__ void head1_kernel(const float* __restrict__ pool,
                             const float* __restrict__ lw1,
                             const float* __restrict__ lb1,
                             float* __restrict__ t1) {
  int gid = blockIdx.x * 256 + threadIdx.x;   // 8192
  int r = gid >> 7, c = gid & 127;
  float acc = lb1[c];
  for (int k = 0; k < 256; ++k) acc += pool[r * 256 + k] * lw1[k * 128 + c];
  t1[gid] = fmaxf(acc, 0.f);
}

__global__ void head2_kernel(const float* __restrict__ t1,
                             const float* __restrict__ lw2,
                             const float* __restrict__ lb2,
                             float* __restrict__ t2) {
  int gid = blockIdx.x * 256 + threadIdx.x;   // 4096
  int r = gid >> 6, c = gid & 63;
  float acc = lb2[c];
  for (int k = 0; k < 128; ++k) acc += t1[r * 128 + k] * lw2[k * 64 + c];
  t2[gid] = fmaxf(acc, 0.f);
}

__global__ __launch_bounds__(256) void head3_kernel(
    const float* __restrict__ t2, const float* __restrict__ lw3,
    const float* __restrict__ lb3, float* __restrict__ out) {
  __shared__ float lg[N_GRAPHS * N_LABELS];
  __shared__ float col[N_LABELS];
  int tid = threadIdx.x;
  for (int o = tid; o < N_GRAPHS * N_LABELS; o += 256) {
    int r = o / N_LABELS, c = o - r * N_LABELS;
    float acc = lb3[c];
    for (int k = 0; k < 64; ++k) acc += t2[r * 64 + k] * lw3[k * N_LABELS + c];
    lg[o] = acc;
  }
  __syncthreads();
  if (tid < N_LABELS) {
    float m = -1e30f;
    for (int r = 0; r < N_GRAPHS; ++r) m = fmaxf(m, lg[r * N_LABELS + tid]);
    float s = 0.f;
    for (int r = 0; r < N_GRAPHS; ++r) s += expf(lg[r * N_LABELS + tid] - m);
    col[tid] = m + logf(s);
  }
  __syncthreads();
  for (int o = tid; o < N_GRAPHS * N_LABELS; o += 256) {
    int c = o % N_LABELS;
    out[o] = lg[o] - col[c];
  }
}

// ---------------- launch ----------------
extern "C" void kernel_launch(void* const* d_in, const int* in_sizes, int n_in,
                              void* d_out, int out_size, void* d_ws, size_t ws_size,
                              hipStream_t stream) {
  const int*   x     = (const int*)  d_in[0];
  const int*   ei    = (const int*)  d_in[1];
  const int*   batch = (const int*)  d_in[2];
  const float* emb   = (const float*)d_in[3];
  const float* w1rel = (const float*)d_in[4];
  const float* w1rt  = (const float*)d_in[5];
  const float* b1    = (const float*)d_in[6];
  const float* w2rel = (const float*)d_in[7];
  const float* w2rt  = (const float*)d_in[8];
  const float* b2    = (const float*)d_in[9];
  const float* lw1   = (const float*)d_in[10];
  const float* lb1   = (const float*)d_in[11];
  const float* lw2   = (const float*)d_in[12];
  const float* lb2   = (const float*)d_in[13];
  const float* lw3   = (const float*)d_in[14];
  const float* lb3   = (const float*)d_in[15];
  float* out = (float*)d_out;

  char* ws = (char*)d_ws;
  const size_t HB   = 51200000;   // N_NODES*FDIM*4
  const size_t OFFB = 400128;     // (N_NODES+1) ints, rounded
  const size_t CSRB = 6400128;    // (N_EDGES+8) ints, rounded
  float* hB      = (float*)(ws);
  float* aggbuf  = (float*)(ws + HB);
  int*   deg     = (int*)  (ws + 2 * HB);
  int*   offsets = (int*)  (ws + 2 * HB + OFFB);
  int*   cursor  = (int*)  (ws + 2 * HB + 2 * OFFB);
  int*   bsum    = (int*)  (ws + 2 * HB + 3 * OFFB);
  int*   csr     = (int*)  (ws + 2 * HB + 3 * OFFB + 2048);
  int*   csr2    = (int*)  (ws + 2 * HB + 3 * OFFB + 2048 + CSRB);
  int*   start   = (int*)  (ws + 2 * HB + 3 * OFFB + 2048 + 2 * CSRB);
  float* zrow    = (float*)(ws + 2 * HB + 3 * OFFB + 2048 + 2 * CSRB + 512);
  float* pool    = (float*)(ws + 2 * HB + 3 * OFFB + 2048 + 2 * CSRB + 512 + 1024);
  float* t1      = (float*)(ws + 2 * HB + 3 * OFFB + 2048 + 2 * CSRB + 512 + 1024 + 65536);
  float* t2      = (float*)(ws + 2 * HB + 3 * OFFB + 2048 + 2 * CSRB + 512 + 1024 + 65536 + 32768);

  init_kernel<<<SCAN_BLOCKS, 256, 0, stream>>>(deg, pool, zrow, csr, csr2);

  count_kernel<<<(N_EDGES + 255) / 256, 256, 0, stream>>>(ei, deg);
  scan1_kernel<<<SCAN_BLOCKS, 256, 0, stream>>>(deg, offsets, bsum);
  scan2_kernel<<<1, 512, 0, stream>>>(bsum);
  scan3_kernel<<<SCAN_BLOCKS, 256, 0, stream>>>(offsets, bsum, cursor);
  fill_kernel<<<(N_EDGES + 255) / 256, 256, 0, stream>>>(ei, x, cursor, csr, csr2);

  // layer 1: aggregate emb rows via csr2 = x[src]; h-term gathered from emb via x
  agg_kernel<<<N_NODES / 8, 256, 0, stream>>>(emb, csr2, offsets, zrow, aggbuf);
  gemm_kernel<<<N_NODES / TN, 256, 0, stream>>>(aggbuf, emb, x, w1rel, w1rt, b1, hB);

  // layer 2: aggregate hB rows via csr; in-place gemm on hB
  agg_kernel<<<N_NODES / 8, 256, 0, stream>>>(hB, csr, offsets, zrow, aggbuf);
  gemm_kernel<<<N_NODES / TN, 256, 0, stream>>>(aggbuf, hB, (const int*)nullptr,
                                                w2rel, w2rt, b2, hB);

  find_starts_kernel<<<SCAN_BLOCKS, 256, 0, stream>>>(batch, start);
  pool_kernel<<<N_GRAPHS * 8, 128, 0, stream>>>(hB, start, pool);
  pool_fin_kernel<<<32, 256, 0, stream>>>(pool, start);

  head1_kernel<<<32, 256, 0, stream>>>(pool, lw1, lb1, t1);
  head2_kernel<<<16, 256, 0, stream>>>(t1, lw2, lb2, t2);
  head3_kernel<<<1, 256, 0, stream>>>(t2, lw3, lb3, out);
}

// Round 4
// 804.628 us; speedup vs baseline: 1.5193x; 1.2347x over previous
//
#include <hip/hip_runtime.h>
#include <hip/hip_bf16.h>

#define N_NODES   100000
#define N_EDGES   1600000
#define N_GRAPHS  64
#define FDIM      128
#define N_LABELS  20
#define SCAN_BLOCKS 391   // ceil(N_NODES/256)

// ---------------- init: zero deg, pool, zrow, csr pads ----------------
__global__ __launch_bounds__(256) void init_kernel(
    int* __restrict__ deg, float* __restrict__ pool, float* __restrict__ zrow,
    int* __restrict__ csr, int* __restrict__ csr2) {
  int i = blockIdx.x * 256 + threadIdx.x;
  if (i < N_NODES) deg[i] = 0;
  if (i < N_GRAPHS * 256) pool[i] = 0.f;
  if (i < FDIM) zrow[i] = 0.f;
  if (i < 8) { csr[N_EDGES + i] = 0; csr2[N_EDGES + i] = 0; }
}

// ---------------- CSR build ----------------
__global__ void count_kernel(const int* __restrict__ ei, int* __restrict__ deg) {
  int e = blockIdx.x * 256 + threadIdx.x;
  if (e < N_EDGES) atomicAdd(&deg[ei[N_EDGES + e]], 1);
}

__global__ __launch_bounds__(256) void scan1_kernel(
    const int* __restrict__ deg, int* __restrict__ offsets,
    int* __restrict__ blockSums) {
  __shared__ int s[256];
  int tid = threadIdx.x;
  int i = blockIdx.x * 256 + tid;
  int v = (i < N_NODES) ? deg[i] : 0;
  s[tid] = v;
  __syncthreads();
  for (int off = 1; off < 256; off <<= 1) {
    int t = (tid >= off) ? s[tid - off] : 0;
    __syncthreads();
    s[tid] += t;
    __syncthreads();
  }
  if (i < N_NODES) offsets[i] = s[tid] - v;       // exclusive within block
  if (tid == 255) blockSums[blockIdx.x] = s[255];
}

__global__ __launch_bounds__(512) void scan2_kernel(int* __restrict__ blockSums) {
  __shared__ int s[512];
  int tid = threadIdx.x;
  int v = (tid < SCAN_BLOCKS) ? blockSums[tid] : 0;
  s[tid] = v;
  __syncthreads();
  for (int off = 1; off < 512; off <<= 1) {
    int t = (tid >= off) ? s[tid - off] : 0;
    __syncthreads();
    s[tid] += t;
    __syncthreads();
  }
  if (tid < SCAN_BLOCKS) blockSums[tid] = s[tid] - v;
}

__global__ __launch_bounds__(256) void scan3_kernel(
    int* __restrict__ offsets, const int* __restrict__ blockSums,
    int* __restrict__ cursor) {
  int i = blockIdx.x * 256 + threadIdx.x;
  if (i < N_NODES) {
    int o = offsets[i] + blockSums[blockIdx.x];
    offsets[i] = o;
    cursor[i] = o;
  }
  if (blockIdx.x == 0 && threadIdx.x == 0) offsets[N_NODES] = N_EDGES;
}

// csr[p] = src node id; csr2[p] = x[src] (emb row for layer-1 gather)
__global__ void fill_kernel(const int* __restrict__ ei, const int* __restrict__ x,
                            int* __restrict__ cursor,
                            int* __restrict__ csr, int* __restrict__ csr2) {
  int e = blockIdx.x * 256 + threadIdx.x;
  if (e < N_EDGES) {
    int s = ei[e];
    int d = ei[N_EDGES + e];
    int p = atomicAdd(&cursor[d], 1);
    csr[p] = s;
    csr2[p] = x[s];
  }
}

// ---------------- aggregation: agg[i,:] = sum_{j->i} feat[srcidx[j],:] ----------------
__global__ __launch_bounds__(256) void agg_kernel(
    const float* __restrict__ feat, const int* __restrict__ srcidx,
    const int* __restrict__ offs, const float* __restrict__ zrow,
    float* __restrict__ aggout) {
  int sub = threadIdx.x >> 5;
  int fq  = threadIdx.x & 31;
  int node = blockIdx.x * 8 + sub;
  const float4* __restrict__ f4 = (const float4*)feat;
  const float4* __restrict__ z4 = (const float4*)zrow;

  float4 acc0 = make_float4(0.f, 0.f, 0.f, 0.f);
  float4 acc1 = make_float4(0.f, 0.f, 0.f, 0.f);
  int s = offs[node], e = offs[node + 1];
  for (int p = s; p < e; p += 8) {
    const float4* rp[8];
#pragma unroll
    for (int u = 0; u < 8; ++u) {
      int iu = srcidx[p + u];                       // safe: padded by 8
      rp[u] = (p + u < e) ? (f4 + (size_t)iu * 32) : z4;
    }
    float4 v0 = rp[0][fq];
    float4 v1 = rp[1][fq];
    float4 v2 = rp[2][fq];
    float4 v3 = rp[3][fq];
    float4 v4 = rp[4][fq];
    float4 v5 = rp[5][fq];
    float4 v6 = rp[6][fq];
    float4 v7 = rp[7][fq];
    acc0.x += v0.x + v2.x + v4.x + v6.x;
    acc0.y += v0.y + v2.y + v4.y + v6.y;
    acc0.z += v0.z + v2.z + v4.z + v6.z;
    acc0.w += v0.w + v2.w + v4.w + v6.w;
    acc1.x += v1.x + v3.x + v5.x + v7.x;
    acc1.y += v1.y + v3.y + v5.y + v7.y;
    acc1.z += v1.z + v3.z + v5.z + v7.z;
    acc1.w += v1.w + v3.w + v5.w + v7.w;
  }
  float4 a = make_float4(acc0.x + acc1.x, acc0.y + acc1.y,
                         acc0.z + acc1.z, acc0.w + acc1.w);
  ((float4*)aggout)[(size_t)node * 32 + fq] = a;
}

// ---------------- GEMM: hout = relu([agg | h] @ [wrel; wroot] + b) ----------------
// 128 nodes x 128 cols per block, 256 threads, 8x8 register tile per thread.
// K-tiled LDS staging: A_s[128][33] (pad -> conflict-free), W_s[32][128]
// (cols strided by 16 per thread -> conflict-free, broadcast).
// In-place hsrc==hout safe: block stages only its own rows, stores at end.
__global__ __launch_bounds__(256) void gemm_kernel(
    const float* __restrict__ agg, const float* __restrict__ hsrc,
    const int* __restrict__ hidx,
    const float* __restrict__ wrel, const float* __restrict__ wroot,
    const float* __restrict__ bias, float* __restrict__ hout) {
  __shared__ float A_s[128][33];
  __shared__ float W_s[32][FDIM];
  int tid = threadIdx.x;
  int nodeBase = blockIdx.x * 128;

  // fixed staging descriptors (4 float4s each for A and W per tile)
  int an[4], aq[4];
  const float* aggp[4];
  const float* hp[4];
#pragma unroll
  for (int i = 0; i < 4; ++i) {
    int f = tid + 256 * i;         // 0..1023
    an[i] = f >> 3;                // node-in-tile 0..127
    aq[i] = f & 7;                 // float4 within 32-float k-slab
    int gn = nodeBase + an[i];
    if (gn > N_NODES - 1) gn = N_NODES - 1;
    aggp[i] = agg + (size_t)gn * FDIM + aq[i] * 4;
    int hr = hidx ? hidx[gn] : gn;
    hp[i] = hsrc + (size_t)hr * FDIM + aq[i] * 4;
  }
  int wk[4], wq[4];
#pragma unroll
  for (int i = 0; i < 4; ++i) {
    int f = tid + 256 * i;
    wk[i] = f >> 5;                // k 0..31
    wq[i] = f & 31;                // float4 within 128-col row
  }

  int tc = tid & 15, tr = tid >> 4;
  float acc[8][8];
#pragma unroll
  for (int j = 0; j < 8; ++j) {
    float b = bias[tc + 16 * j];
#pragma unroll
    for (int i = 0; i < 8; ++i) acc[i][j] = b;
  }

  for (int k0 = 0; k0 < 2 * FDIM; k0 += 32) {
    __syncthreads();
    // stage A slab (k0..k0+31 of the 256-wide [agg | h] row)
#pragma unroll
    for (int i = 0; i < 4; ++i) {
      const float* src = (k0 < FDIM) ? (aggp[i] + k0) : (hp[i] + (k0 - FDIM));
      float4 v = *(const float4*)src;
      float* d = &A_s[an[i]][aq[i] * 4];
      d[0] = v.x; d[1] = v.y; d[2] = v.z; d[3] = v.w;
    }
    // stage W slab
    const float* W = (k0 < FDIM) ? (wrel + (size_t)k0 * FDIM)
                                 : (wroot + (size_t)(k0 - FDIM) * FDIM);
#pragma unroll
    for (int i = 0; i < 4; ++i) {
      float4 v = *(const float4*)(W + (size_t)wk[i] * FDIM + wq[i] * 4);
      *(float4*)&W_s[wk[i]][wq[i] * 4] = v;
    }
    __syncthreads();

#pragma unroll 4
    for (int k = 0; k < 32; ++k) {
      float a[8], w[8];
#pragma unroll
      for (int i = 0; i < 8; ++i) a[i] = A_s[tr * 8 + i][k];
#pragma unroll
      for (int j = 0; j < 8; ++j) w[j] = W_s[k][tc + 16 * j];
#pragma unroll
      for (int i = 0; i < 8; ++i)
#pragma unroll
        for (int j = 0; j < 8; ++j)
          acc[i][j] += a[i] * w[j];
    }
  }

  // epilogue: relu + store (cols strided by 16; lanes tc are consecutive)
#pragma unroll
  for (int i = 0; i < 8; ++i) {
    int n = nodeBase + tr * 8 + i;
    if (n < N_NODES) {
      float* o = hout + (size_t)n * FDIM + tc;
#pragma unroll
      for (int j = 0; j < 8; ++j)
        o[16 * j] = fmaxf(acc[i][j], 0.f);
    }
  }
}

// ---------------- per-graph segment boundaries (batch is sorted) ----------------
__global__ void find_starts_kernel(const int* __restrict__ batch,
                                   int* __restrict__ start) {
  int i = blockIdx.x * 256 + threadIdx.x;
  if (i >= N_NODES) return;
  int b  = batch[i];
  int bp = (i == 0) ? -1 : batch[i - 1];
  for (int g = bp + 1; g <= b; ++g) start[g] = i;
  if (i == N_NODES - 1) {
    for (int g = b + 1; g <= N_GRAPHS; ++g) start[g] = N_NODES;
  }
}

// ---------------- pooling: max & sum per graph ----------------
__global__ __launch_bounds__(128) void pool_kernel(
    const float* __restrict__ h2, const int* __restrict__ start,
    float* __restrict__ pool) {
  int g = blockIdx.x >> 3;
  int c = blockIdx.x & 7;
  int f = threadIdx.x;
  int s = start[g], e = start[g + 1];
  int len = e - s;
  int lo = s + (int)(((long long)len * c) >> 3);
  int hi = s + (int)(((long long)len * (c + 1)) >> 3);
  float mx = 0.f, sm = 0.f;
  for (int n = lo; n < hi; ++n) {
    float v = h2[(size_t)n * FDIM + f];
    mx = fmaxf(mx, v);
    sm += v;
  }
  atomicMax((unsigned int*)&pool[g * 256 + f], __float_as_uint(mx));
  atomicAdd(&pool[g * 256 + 128 + f], sm);
}

__global__ void pool_fin_kernel(float* __restrict__ pool,
                                const int* __restrict__ start) {
  int gid = blockIdx.x * 256 + threadIdx.x;   // 8192
  int g = gid >> 7, f = gid & 127;
  int cnt = start[g + 1] - start[g];
  float c = (float)(cnt > 1 ? cnt : 1);
  pool[g * 256 + 128 + f] /= c;
}

// ---------------- MLP head ----------------
__global__ void head1_kernel(const float* __restrict__ pool,
                             const float* __restrict__ lw1,
                             const float* __restrict__ lb1,
                             float* __restrict__ t1) {
  int gid = blockIdx.x * 256 + threadIdx.x;   // 8192
  int r = gid >> 7, c = gid & 127;
  float acc = lb1[c];
  for (int k = 0; k < 256; ++k) acc += pool[r * 256 + k] * lw1[k * 128 + c];
  t1[gid] = fmaxf(acc, 0.f);
}

__global__ void head2_kernel(const float* __restrict__ t1,
                             const float* __restrict__ lw2,
                             const float* __restrict__ lb2,
                             float* __restrict__ t2) {
  int gid = blockIdx.x * 256 + threadIdx.x;   // 4096
  int r = gid >> 6, c = gid & 63;
  float acc = lb2[c];
  for (int k = 0; k < 128; ++k) acc += t1[r * 128 + k] * lw2[k * 64 + c];
  t2[gid] = fmaxf(acc, 0.f);
}

__global__ __launch_bounds__(256) void head3_kernel(
    const float* __restrict__ t2, const float* __restrict__ lw3,
    const float* __restrict__ lb3, float* __restrict__ out) {
  __shared__ float lg[N_GRAPHS * N_LABELS];
  __shared__ float col[N_LABELS];
  int tid = threadIdx.x;
  for (int o = tid; o < N_GRAPHS * N_LABELS; o += 256) {
    int r = o / N_LABELS, c = o - r * N_LABELS;
    float acc = lb3[c];
    for (int k = 0; k < 64; ++k) acc += t2[r * 64 + k] * lw3[k * N_LABELS + c];
    lg[o] = acc;
  }
  __syncthreads();
  if (tid < N_LABELS) {
    float m = -1e30f;
    for (int r = 0; r < N_GRAPHS; ++r) m = fmaxf(m, lg[r * N_LABELS + tid]);
    float s = 0.f;
    for (int r = 0; r < N_GRAPHS; ++r) s += expf(lg[r * N_LABELS + tid] - m);
    col[tid] = m + logf(s);
  }
  __syncthreads();
  for (int o = tid; o < N_GRAPHS * N_LABELS; o += 256) {
    int c = o % N_LABELS;
    out[o] = lg[o] - col[c];
  }
}

// ---------------- launch ----------------
extern "C" void kernel_launch(void* const* d_in, const int* in_sizes, int n_in,
                              void* d_out, int out_size, void* d_ws, size_t ws_size,
                              hipStream_t stream) {
  const int*   x     = (const int*)  d_in[0];
  const int*   ei    = (const int*)  d_in[1];
  const int*   batch = (const int*)  d_in[2];
  const float* emb   = (const float*)d_in[3];
  const float* w1rel = (const float*)d_in[4];
  const float* w1rt  = (const float*)d_in[5];
  const float* b1    = (const float*)d_in[6];
  const float* w2rel = (const float*)d_in[7];
  const float* w2rt  = (const float*)d_in[8];
  const float* b2    = (const float*)d_in[9];
  const float* lw1   = (const float*)d_in[10];
  const float* lb1   = (const float*)d_in[11];
  const float* lw2   = (const float*)d_in[12];
  const float* lb2   = (const float*)d_in[13];
  const float* lw3   = (const float*)d_in[14];
  const float* lb3   = (const float*)d_in[15];
  float* out = (float*)d_out;

  char* ws = (char*)d_ws;
  const size_t HB   = 51200000;   // N_NODES*FDIM*4
  const size_t OFFB = 400128;     // (N_NODES+1) ints, rounded
  const size_t CSRB = 6400128;    // (N_EDGES+8) ints, rounded
  float* hB      = (float*)(ws);
  float* aggbuf  = (float*)(ws + HB);
  int*   deg     = (int*)  (ws + 2 * HB);
  int*   offsets = (int*)  (ws + 2 * HB + OFFB);
  int*   cursor  = (int*)  (ws + 2 * HB + 2 * OFFB);
  int*   bsum    = (int*)  (ws + 2 * HB + 3 * OFFB);
  int*   csr     = (int*)  (ws + 2 * HB + 3 * OFFB + 2048);
  int*   csr2    = (int*)  (ws + 2 * HB + 3 * OFFB + 2048 + CSRB);
  int*   start   = (int*)  (ws + 2 * HB + 3 * OFFB + 2048 + 2 * CSRB);
  float* zrow    = (float*)(ws + 2 * HB + 3 * OFFB + 2048 + 2 * CSRB + 512);
  float* pool    = (float*)(ws + 2 * HB + 3 * OFFB + 2048 + 2 * CSRB + 512 + 1024);
  float* t1      = (float*)(ws + 2 * HB + 3 * OFFB + 2048 + 2 * CSRB + 512 + 1024 + 65536);
  float* t2      = (float*)(ws + 2 * HB + 3 * OFFB + 2048 + 2 * CSRB + 512 + 1024 + 65536 + 32768);

  init_kernel<<<SCAN_BLOCKS, 256, 0, stream>>>(deg, pool, zrow, csr, csr2);

  count_kernel<<<(N_EDGES + 255) / 256, 256, 0, stream>>>(ei, deg);
  scan1_kernel<<<SCAN_BLOCKS, 256, 0, stream>>>(deg, offsets, bsum);
  scan2_kernel<<<1, 512, 0, stream>>>(bsum);
  scan3_kernel<<<SCAN_BLOCKS, 256, 0, stream>>>(offsets, bsum, cursor);
  fill_kernel<<<(N_EDGES + 255) / 256, 256, 0, stream>>>(ei, x, cursor, csr, csr2);

  // layer 1: aggregate emb rows via csr2 = x[src]; h-term gathered from emb via x
  agg_kernel<<<N_NODES / 8, 256, 0, stream>>>(emb, csr2, offsets, zrow, aggbuf);
  gemm_kernel<<<(N_NODES + 127) / 128, 256, 0, stream>>>(aggbuf, emb, x,
                                                         w1rel, w1rt, b1, hB);

  // layer 2: aggregate hB rows via csr; in-place gemm on hB
  agg_kernel<<<N_NODES / 8, 256, 0, stream>>>(hB, csr, offsets, zrow, aggbuf);
  gemm_kernel<<<(N_NODES + 127) / 128, 256, 0, stream>>>(aggbuf, hB,
                                                         (const int*)nullptr,
                                                         w2rel, w2rt, b2, hB);

  find_starts_kernel<<<SCAN_BLOCKS, 256, 0, stream>>>(batch, start);
  pool_kernel<<<N_GRAPHS * 8, 128, 0, stream>>>(hB, start, pool);
  pool_fin_kernel<<<32, 256, 0, stream>>>(pool, start);

  head1_kernel<<<32, 256, 0, stream>>>(pool, lw1, lb1, t1);
  head2_kernel<<<16, 256, 0, stream>>>(t1, lw2, lb2, t2);
  head3_kernel<<<1, 256, 0, stream>>>(t2, lw3, lb3, out);
}